// Round 11
// baseline (249.860 us; speedup 1.0000x reference)
//
#include <hip/hip_runtime.h>
#include <hip/hip_bf16.h>
#include <math.h>

// ---------------------------------------------------------------------------
// DIM=256 HEADS=16 DHEAD=16 H=12 W=26 (HW=312)  Hk=3 Wk=6 (J=18)  B=256
// q_map[b,c,s] = q[b,(c*56+s)&255]
// Round 18: r17 + ILP/conflict edits exploiting LB(512,2)'s 256-reg cap
// (we're at 116 -> headroom):
//  1. q_sb -> q_sb4[4][272] bank-rotated replicas: sim gathers were 64
//     lanes on a 512B table (qd0/qd2 bank-aliased, 2-4 way). 272-ushort
//     stride = 8-bank rotation; + per-qd ka offset (224 ushorts = +16
//     banks) puts the 4 qd octets on disjoint bank ranges -> conflict-free.
//  2. CPB W1 weights back to REGISTERS (48 regs, r7's proven design at
//     this exact launch shape) -- removes 8 LDS reads per mlp1 x45/wave.
//  3. mlp2 2-tile interleave (r7 pattern): F0/F1 gathers for both tiles
//     issued together; GEMM2+GEMM3 chains of 2 tiles interleaved per mtl
//     -> 2-4 independent MFMA chains in flight.
// Everything else identical to r17 (passed, absmax 0.015625, dur 127us).
// Revert trigger: VGPR>200 or WRITE_SIZE >> 256KB (spill signature).
// ---------------------------------------------------------------------------

typedef __attribute__((ext_vector_type(8))) short short8;   // 8 bf16
typedef __attribute__((ext_vector_type(4))) short s4bf;     // 4 bf16
typedef __attribute__((ext_vector_type(4))) float floatx4;

union U16 { uint4 u; short8 s; };
union U8b { unsigned int u[2]; s4bf s; };

#define MFMA(A, B, C) __builtin_amdgcn_mfma_f32_16x16x32_bf16((A), (B), (C), 0, 0, 0)
#define MFMA16(A, B, C) __builtin_amdgcn_mfma_f32_16x16x16bf16_1k((A), (B), (C), 0, 0, 0)

__device__ __forceinline__ unsigned int f2bf(float f) {   // RNE f32->bf16 (low 16)
    unsigned int u = __float_as_uint(f);
    u += 0x7fffu + ((u >> 16) & 1u);
    return u >> 16;
}
__device__ __forceinline__ unsigned int pk2(float a, float b) {   // HW cvt_pk
    __hip_bfloat162 h = __float22bfloat162_rn(make_float2(a, b));
    union { __hip_bfloat162 h; unsigned int u; } cv; cv.h = h;
    return cv.u;
}
__device__ __forceinline__ float bf2f(unsigned short v) {
    return __uint_as_float((unsigned int)v << 16);
}
__device__ __forceinline__ uint4 pack8(float4 a, float4 b) {
    uint4 r;
    r.x = pk2(a.x, a.y); r.y = pk2(a.z, a.w);
    r.z = pk2(b.x, b.y); r.w = pk2(b.z, b.w);
    return r;
}

// ===========================================================================
__global__ __launch_bounds__(512, 2) void k_all(
    const float* __restrict__ x, const float* __restrict__ q,
    const float* __restrict__ w_dw, const float* __restrict__ b_dw,
    const float* __restrict__ w_pw,
    const float* __restrict__ wk, const float* __restrict__ wv,
    const float* __restrict__ w_out, const float* __restrict__ b_out,
    const float* __restrict__ cw1, const float* __restrict__ cb1,
    const float* __restrict__ cw2, const float* __restrict__ cb2,
    const float* __restrict__ cw3, const float* __restrict__ cb3,
    const float* __restrict__ conv_w, const float* __restrict__ conv_b,
    const float* __restrict__ ln_g, const float* __restrict__ ln_b,
    float* __restrict__ out)
{
    const int b = blockIdx.x, tid = threadIdx.x;
    const int w = tid >> 6, lane = tid & 63;
    const int n = lane & 15, qd = lane >> 4;

    // ---- persistent LDS (~21.5 KB) ----
    __shared__ float qf_s[256];
    __shared__ unsigned short q_sb4[1088];          // 4 bank-rotated replicas
    __shared__ unsigned short v_sb[5120];           // v bf16 [256][20]
    __shared__ float F0[468], F1[216];              // log tables [26][18], [12][18]
    __shared__ unsigned int lutxy[312];             // ix | iy<<16
    __shared__ float off_s[36], n0_s[18], n1_s[18];
    __shared__ float sx0[18], sy0[18], swx[18], swy[18];
    __shared__ float b2_s[64], b3_s[16];
    __shared__ float wA_s[288];
    __shared__ __align__(16) float m_s[256];
    __shared__ float pooled_s[256], redb[24];
    // ---- union region (117504 B): S triple buffer, 3 x [32][18][17] f32 ----
    __shared__ __align__(16) unsigned char UB[117504];
    float* Sbuf = (float*)UB;
    unsigned short* kvT = (unsigned short*)UB;       // [18 j][264 c] bf16 9504B
    float* qsw = (float*)UB;                         // 16 copies x 258 = 16512B
    float* t_s = (float*)(UB + 16512);               // [18 p][256 c] 18432B
    unsigned short* k_sb = (unsigned short*)(UB + 16512);  // k bf16 [256][20]
    float* wred = (float*)(UB + 39168);              // S1 region: 512x18 f32

    // ---- stage 0 ----
    if (tid < 256) {
        const float qv = q[b * 256 + tid];
        qf_s[tid] = qv;
        const unsigned short qb = (unsigned short)f2bf(qv * 0.25f);
        q_sb4[tid] = qb; q_sb4[272 + tid] = qb;
        q_sb4[544 + tid] = qb; q_sb4[816 + tid] = qb;
    }
    for (int u = tid; u < 4128; u += 512) {
        const int r = u / 258, i = u - r * 258;
        qsw[u] = (i < 256) ? q[b * 256 + i] : 0.f;
    }
    if (tid < 312) {
        const int iy = tid / 26;
        lutxy[tid] = (unsigned int)(tid - iy * 26) | ((unsigned int)iy << 16);
    }
    if (tid < 64) b2_s[tid] = cb2[tid];
    if (tid < 16) b3_s[tid] = cb3[tid];
    __syncthreads();

    // ---- depthwise conv 6x6 s4 p1 + GELU -> t_s ----
    {
        const int c = tid & 255, g = tid >> 8;     // g: jw-half
        float wreg[36];
        const float4* wdw4 = (const float4*)w_dw;  // [c][36] contiguous
        #pragma unroll
        for (int i = 0; i < 9; ++i) {
            const float4 t4 = wdw4[c * 9 + i];
            wreg[i * 4 + 0] = t4.x; wreg[i * 4 + 1] = t4.y;
            wreg[i * 4 + 2] = t4.z; wreg[i * 4 + 3] = t4.w;
        }
        float acc[9];
        const float bv = b_dw[c];
        #pragma unroll
        for (int a = 0; a < 9; ++a) acc[a] = bv;
        const int cb = (c * 56) & 255;
        const int cp = (c & 15) * 258;
        for (int jh = 0; jh < 3; ++jh) {
            for (int kh = 0; kh < 6; ++kh) {
                const int ih = jh * 4 - 1 + kh;
                if (ih < 0 || ih >= 12) continue;
                const int rb = ih * 26;
                #pragma unroll
                for (int jwl = 0; jwl < 3; ++jwl) {
                    const int jw = g * 3 + jwl;
                    #pragma unroll
                    for (int kw = 0; kw < 6; ++kw) {
                        const int iw = jw * 4 - 1 + kw;
                        if (iw < 0 || iw >= 26) continue;
                        acc[jh * 3 + jwl] += wreg[kh * 6 + kw] * qsw[cp + ((cb + rb + iw) & 255)];
                    }
                }
            }
        }
        #pragma unroll
        for (int a = 0; a < 9; ++a) {
            const int jh = a / 3, jwl = a - jh * 3;
            const int p = jh * 6 + g * 3 + jwl;
            const float v = acc[a];
            t_s[p * 256 + c] = 0.5f * v * (1.0f + erff(v * 0.70710678118654752f));
        }
    }
    __syncthreads();

    // ---- offsets: 36 dots over 256 channels ----
    for (int oi = w; oi < 36; oi += 8) {
        const int o = oi / 18, p = oi - o * 18;
        float s = 0.f;
        for (int c = lane; c < 256; c += 64) s += w_pw[o * 256 + c] * t_s[p * 256 + c];
        for (int d = 32; d > 0; d >>= 1) s += __shfl_down(s, d, 64);
        if (lane == 0) off_s[oi] = 4.0f * tanhf(s);
    }
    __syncthreads();

    // ---- grid coords + bilinear params ----
    if (tid < 18) {
        const int j = tid, jh = j / 6, jw = j - jh * 6;
        const float vg0 = (float)jw + off_s[j];
        const float vg1 = (float)jh + off_s[18 + j];
        const float n0 = 2.0f * vg0 / 2.0f - 1.0f;
        const float n1 = 2.0f * vg1 / 5.0f - 1.0f;
        n0_s[j] = n0; n1_s[j] = n1;
        const float xp = ((n0 + 1.0f) * 26.0f - 1.0f) * 0.5f;
        const float yp = ((n1 + 1.0f) * 12.0f - 1.0f) * 0.5f;
        const float x0 = floorf(xp), y0 = floorf(yp);
        sx0[j] = x0; sy0[j] = y0; swx[j] = xp - x0; swy[j] = yp - y0;
    }
    __syncthreads();

    // ---- bilinear sample -> kvT bf16 [j][264]; F0/F1 log tables ----
    {
        const int c = tid & 255, g = tid >> 8;
        const float* xb = x + ((size_t)b * 256 + c) * 312;
        for (int jj = 0; jj < 9; ++jj) {
            const int j = g * 9 + jj;
            const int x0 = (int)sx0[j], y0 = (int)sy0[j];
            const int x1 = x0 + 1, y1 = y0 + 1;
            const float wx1 = swx[j], wy1 = swy[j];
            const float wx0 = 1.f - wx1, wy0 = 1.f - wy1;
            const bool xv0 = (x0 >= 0) & (x0 < 26), xv1 = (x1 >= 0) & (x1 < 26);
            const bool yv0 = (y0 >= 0) & (y0 < 12), yv1 = (y1 >= 0) & (y1 < 12);
            const float v00 = (xv0 & yv0) ? xb[y0 * 26 + x0] : 0.f;
            const float v01 = (xv1 & yv0) ? xb[y0 * 26 + x1] : 0.f;
            const float v10 = (xv0 & yv1) ? xb[y1 * 26 + x0] : 0.f;
            const float v11 = (xv1 & yv1) ? xb[y1 * 26 + x1] : 0.f;
            const float val = wy0 * (wx0 * v00 + wx1 * v01) + wy1 * (wx0 * v10 + wx1 * v11);
            kvT[j * 264 + c] = (unsigned short)f2bf(val);
        }
    }
    for (int u = tid; u < 684; u += 512) {
        if (u < 468) {
            const int ixv = u / 18, j = u - ixv * 18;
            const float p0 = (float)ixv * (2.0f / 11.0f) - 1.0f - n0_s[j];
            F0[u] = copysignf(__logf(1.0f + fabsf(p0)), p0);
        } else {
            const int u2 = u - 468;
            const int iyv = u2 / 18, j = u2 - iyv * 18;
            const float p1 = (float)iyv * (2.0f / 25.0f) - 1.0f - n1_s[j];
            F1[u2] = copysignf(__logf(1.0f + fabsf(p1)), p1);
        }
    }
    __syncthreads();

    // ---- k/v projection via MFMA: wave w -> matrix (w&1), mtb = w>>1 ----
    {
        const int m2 = w & 1, mtb = w >> 1;
        const float4* wm4 = (const float4*)(m2 ? wv : wk);
        floatx4 pa[4][2];
        #pragma unroll
        for (int a = 0; a < 4; ++a) {
            pa[a][0] = (floatx4){0.f, 0.f, 0.f, 0.f};
            pa[a][1] = (floatx4){0.f, 0.f, 0.f, 0.f};
        }
        #pragma unroll 2
        for (int ks = 0; ks < 8; ++ks) {
            U16 b0, b1;
            b0.u = *(const uint4*)(kvT + n * 264 + ks * 32 + qd * 8);
            b1.u = make_uint4(0u, 0u, 0u, 0u);
            if (n < 2) b1.u = *(const uint4*)(kvT + (16 + n) * 264 + ks * 32 + qd * 8);
            #pragma unroll
            for (int mtl = 0; mtl < 4; ++mtl) {
                const int mt = mtb + mtl * 4;
                const int f4i = (mt * 16 + n) * 64 + ks * 8 + qd * 2;
                U16 A; A.u = pack8(wm4[f4i], wm4[f4i + 1]);
                pa[mtl][0] = MFMA(A.s, b0.s, pa[mtl][0]);
                pa[mtl][1] = MFMA(A.s, b1.s, pa[mtl][1]);
            }
        }
        unsigned short* dst = m2 ? v_sb : k_sb;
        #pragma unroll
        for (int mtl = 0; mtl < 4; ++mtl) {
            const int mt = mtb + mtl * 4;
            #pragma unroll
            for (int r = 0; r < 4; ++r) {
                const int o = mt * 16 + qd * 4 + r;
                dst[o * 20 + n] = (unsigned short)f2bf(pa[mtl][0][r]);
                if (n < 2) dst[o * 20 + 16 + n] = (unsigned short)f2bf(pa[mtl][1][r]);
            }
        }
    }
    __syncthreads();

    // ---- per-lane weight fragments (late load) ----
    uint4 W2f[4][2];
    unsigned int W3h[4][2];                          // K=16 A-frags for GEMM3
    {
        const float4* cw2_4 = (const float4*)cw2;
        #pragma unroll
        for (int mtl = 0; mtl < 4; ++mtl)
            #pragma unroll
            for (int ks = 0; ks < 2; ++ks) {
                const int base = (mtl * 16 + n) * 16 + ks * 8 + qd * 2;
                W2f[mtl][ks] = pack8(cw2_4[base], cw2_4[base + 1]);
            }
        const float4* cw3_4 = (const float4*)cw3;
        #pragma unroll
        for (int kc = 0; kc < 4; ++kc) {
            const float4 v = cw3_4[n * 16 + kc * 4 + qd];  // cw3[n*64+kc*16+qd*4..]
            W3h[kc][0] = pk2(v.x, v.y);
            W3h[kc][1] = pk2(v.z, v.w);
        }
    }
    // CPB layer-1 weights in registers (r7-proven at this launch shape)
    float W1a[16], W1b[16], B1r[16];
    #pragma unroll
    for (int kk = 0; kk < 16; ++kk) {
        const int kid = (kk < 8) ? (qd * 8 + kk) : (32 + qd * 8 + kk - 8);
        W1a[kk] = cw1[kid * 2]; W1b[kk] = cw1[kid * 2 + 1]; B1r[kk] = cb1[kid];
    }

    // ---- Bk fragments for sim via MFMA16: lane (n,qd) col j=jt*16+n, k=qd*4+e
    unsigned int Bk16[2][2][2];                      // [hh][jt][2 uints]
    #pragma unroll
    for (int hh = 0; hh < 2; ++hh)
        #pragma unroll
        for (int jt = 0; jt < 2; ++jt) {
            unsigned int u0 = 0, u1 = 0;
            const int j = jt * 16 + n;
            if (j < 18) {
                const int h = w * 2 + hh;
                const int cb0 = (h * 16 + qd * 4) * 20 + j;
                u0 = (unsigned)k_sb[cb0]      | ((unsigned)k_sb[cb0 + 20] << 16);
                u1 = (unsigned)k_sb[cb0 + 40] | ((unsigned)k_sb[cb0 + 60] << 16);
            }
            Bk16[hh][jt][0] = u0; Bk16[hh][jt][1] = u1;
        }
    // A-gather base constants: ((h*16+qd*4)*56) & 255 per hh
    int kA[2];
    #pragma unroll
    for (int hh = 0; hh < 2; ++hh)
        kA[hh] = (((w * 2 + hh) * 16 + qd * 4) * 56) & 255;
    __syncthreads();   // k_sb dead; S triple buffer live from here

    // ---- 3-stage pipelined chunk loop: 12 intervals, 1 barrier each ----
    float wAcc[18];
    #pragma unroll
    for (int j = 0; j < 18; ++j) wAcc[j] = 0.f;

    auto soft_acc = [&](int chp, const float* Sp) {
        const int il = tid >> 4, h = tid & 15;
        const int CIp = (chp == 9) ? 24 : 32;
        if (il < CIp) {
            const float cwv = conv_w[chp * 32 + il];
            float lv[18];
            const float* row = Sp + (il * 18) * 17 + h;
            #pragma unroll
            for (int j = 0; j < 18; ++j) lv[j] = row[j * 17];
            // pairwise-tree max (depth ~5 vs 17)
            float mx[9];
            #pragma unroll
            for (int p = 0; p < 9; ++p) mx[p] = fmaxf(lv[2 * p], lv[2 * p + 1]);
            #pragma unroll
            for (int p = 0; p < 4; ++p) mx[p] = fmaxf(mx[p], mx[p + 4]);
            mx[0] = fmaxf(mx[0], mx[2]); mx[1] = fmaxf(mx[1], mx[3]);
            const float m = fmaxf(fmaxf(mx[0], mx[1]), mx[8]);
            // exp + 2-way partial sums (chain 9 vs 18)
            float sa = 0.f, sb = 0.f;
            #pragma unroll
            for (int j = 0; j < 18; j += 2) {
                lv[j] = __expf(lv[j] - m);     sa += lv[j];
                lv[j + 1] = __expf(lv[j + 1] - m); sb += lv[j + 1];
            }
            const float wgt = cwv / (sa + sb);
            #pragma unroll
            for (int j = 0; j < 18; ++j) wAcc[j] = fmaf(wgt, lv[j], wAcc[j]);
        }
    };

    for (int t = 0; t < 12; ++t) {
        // (a) sim(t) -> S[t%3]  — MFMA16, conflict-free replica gathers
        if (t < 10) {
            float* Sc = Sbuf + (t % 3) * 9792;
            const int ibase = t * 32;
            const unsigned short* qsb = q_sb4 + qd * 272;
            #pragma unroll
            for (int hh = 0; hh < 2; ++hh) {
                const int h = w * 2 + hh;
                const int ka = kA[hh];
                #pragma unroll
                for (int ig = 0; ig < 2; ++ig) {
                    const int ii = ibase + ig * 16 + n;
                    const unsigned int a0 =
                        (unsigned)qsb[(ka + ii) & 255] |
                        ((unsigned)qsb[(ka + 56 + ii) & 255] << 16);
                    const unsigned int a1 =
                        (unsigned)qsb[(ka + 112 + ii) & 255] |
                        ((unsigned)qsb[(ka + 168 + ii) & 255] << 16);
                    U8b Af; Af.u[0] = a0; Af.u[1] = a1;
                    #pragma unroll
                    for (int jt = 0; jt < 2; ++jt) {
                        U8b Bf; Bf.u[0] = Bk16[hh][jt][0]; Bf.u[1] = Bk16[hh][jt][1];
                        floatx4 D = {0.f, 0.f, 0.f, 0.f};
                        D = MFMA16(Af.s, Bf.s, D);
                        const int j = jt * 16 + n;
                        if (j < 18) {
                            #pragma unroll
                            for (int r = 0; r < 4; ++r)
                                Sc[((ig * 16 + qd * 4 + r) * 18 + j) * 17 + h] = D[r];
                        }
                    }
                }
            }
        }
        // (b) mlp(t-1) RMW S[(t-1)%3] — 2-tile interleave, fused GEMM2->GEMM3
        if (t >= 1 && t < 11) {
            const int chm = t - 1;
            float* Sm = Sbuf + (chm % 3) * 9792;
            const int ibase = chm * 32;
            auto mlp2 = [&](int tA, int tB, bool two) {
                int igv[2], jv[2];
                float f0v[2], f1v[2];
                #pragma unroll
                for (int u = 0; u < 2; ++u) {
                    const int tt = u ? tB : tA;
                    const int ig = (tt >= 18) ? 1 : 0;
                    const int j = tt - ig * 18;
                    igv[u] = ig; jv[u] = j;
                    const int i0 = ibase + ig * 16 + n;
                    const unsigned int lv2 = lutxy[(i0 < 312) ? i0 : 311];
                    const int ix = (int)(lv2 & 0xffffu), iy = (int)(lv2 >> 16);
                    f0v[u] = F0[ix * 18 + j];
                    f1v[u] = F1[iy * 18 + j];
                }
                U16 ub0[2], ub1[2];
                #pragma unroll
                for (int u = 0; u < 2; ++u) {
                    unsigned int uu[8];
                    #pragma unroll
                    for (int kp = 0; kp < 8; ++kp) {
                        const float ha = fmaxf(fmaf(W1a[2*kp],   f0v[u], fmaf(W1b[2*kp],   f1v[u], B1r[2*kp])),   0.f);
                        const float hb = fmaxf(fmaf(W1a[2*kp+1], f0v[u], fmaf(W1b[2*kp+1], f1v[u], B1r[2*kp+1])), 0.f);
                        uu[kp] = pk2(ha, hb);
                    }
                    ub0[u].u = make_uint4(uu[0], uu[1], uu[2], uu[3]);
                    ub1[u].u = make_uint4(uu[4], uu[5], uu[6], uu[7]);
                }
                floatx4 a3a[2], a3b[2];
                #pragma unroll
                for (int u = 0; u < 2; ++u) {
                    a3a[u] = (floatx4){0.f, 0.f, 0.f, 0.f};
                    a3b[u] = (floatx4){0.f, 0.f, 0.f, 0.f};
                }
                #pragma unroll
                for (int mtl = 0; mtl < 4; ++mtl) {
                    U16 A0, A1; A0.u = W2f[mtl][0]; A1.u = W2f[mtl][1];
                    #pragma unroll
                    for (int u = 0; u < 2; ++u) {
                        if (u == 1 && !two) break;
                        floatx4 acc = {0.f, 0.f, 0.f, 0.f};
                        acc = MFMA(A0.s, ub0[u].s, acc);
                        acc = MFMA(A1.s, ub1[u].s, acc);
                        U8b Bf3, Af3;
                        Bf3.u[0] = pk2(fmaxf(acc[0] + b2_s[mtl*16 + qd*4 + 0], 0.f),
                                       fmaxf(acc[1] + b2_s[mtl*16 + qd*4 + 1], 0.f));
                        Bf3.u[1] = pk2(fmaxf(acc[2] + b2_s[mtl*16 + qd*4 + 2], 0.f),
                                       fmaxf(acc[3] + b2_s[mtl*16 + qd*4 + 3], 0.f));
                        Af3.u[0] = W3h[mtl][0]; Af3.u[1] = W3h[mtl][1];
                        if (mtl & 1) a3b[u] = MFMA16(Af3.s, Bf3.s, a3b[u]);
                        else         a3a[u] = MFMA16(Af3.s, Bf3.s, a3a[u]);
                    }
                }
                #pragma unroll
                for (int u = 0; u < 2; ++u) {
                    if (u == 1 && !two) break;
                    float* sp = Sm + ((igv[u] * 16 + n) * 18 + jv[u]) * 17 + qd * 4;
                    #pragma unroll
                    for (int r = 0; r < 4; ++r)
                        sp[r] = a3a[u][r] + a3b[u][r] + b3_s[qd * 4 + r] + sp[r];
                }
            };
            mlp2(w, w + 8, true);
            mlp2(w + 16, w + 24, true);
            if (w < 4) mlp2(32 + w, 32 + w, false);
        }
        // (c) soft(t-2) reads S[(t-2)%3]
        if (t >= 2) soft_acc(t - 2, Sbuf + ((t - 2) % 3) * 9792);
        __syncthreads();
    }

    // ---- reduce wAcc over 32 il-slots -> wA_s[h][j]; conv_w sum ----
    // wred sits in S1 region; last soft read S0 (chunk 9, 9%3=0).
    #pragma unroll
    for (int j = 0; j < 18; ++j) wred[tid * 18 + j] = wAcc[j];
    {
        float v = 0.f;
        for (int u = tid; u < 312; u += 512) v += conv_w[u];
        for (int d = 32; d > 0; d >>= 1) v += __shfl_down(v, d, 64);
        if (lane == 0) redb[w] = v;
    }
    __syncthreads();
    for (int u = tid; u < 288; u += 512) {
        const int h = u / 18, j = u - h * 18;
        float s = 0.f;
        #pragma unroll
        for (int sl = 0; sl < 32; ++sl) s += wred[(sl * 16 + h) * 18 + j];
        wA_s[u] = s;
    }
    __syncthreads();

    // ---- m[c] = sum_j wA[h][j] * v[c][j] ----
    if (tid < 256) {
        const int hb = (tid >> 4) * 18;
        float acc = 0.f;
        #pragma unroll
        for (int j = 0; j < 18; ++j) acc += wA_s[hb + j] * bf2f(v_sb[tid * 20 + j]);
        m_s[tid] = acc;
    }
    __syncthreads();

    float Ssum = 0.f;
    #pragma unroll
    for (int i = 0; i < 8; ++i) Ssum += redb[i];

    // ---- pooled = w_out . m  (8 waves x 32 rows, coalesced float4) ----
    {
        const float4 mm = *(const float4*)(m_s + lane * 4);
        for (int ol = 0; ol < 32; ++ol) {
            const int o = w * 32 + ol;
            const float4 wq = *(const float4*)(w_out + o * 256 + lane * 4);
            float d = wq.x * mm.x + wq.y * mm.y + wq.z * mm.z + wq.w * mm.w;
            for (int dd = 32; dd > 0; dd >>= 1) d += __shfl_down(d, dd, 64);
            if (lane == 0) pooled_s[o] = d;
        }
    }
    __syncthreads();

    // ---- residual + LayerNorm (first 4 waves) ----
    if (tid < 256) {
        const float y = pooled_s[tid] + b_out[tid] * Ssum + conv_b[0] + qf_s[tid];
        float s1 = y, s2 = y * y;
        for (int d = 32; d > 0; d >>= 1) { s1 += __shfl_down(s1, d, 64); s2 += __shfl_down(s2, d, 64); }
        if (lane == 0) { redb[16 + w] = s1; redb[20 + w] = s2; }
    }
    __syncthreads();
    if (tid < 256) {
        const float y = pooled_s[tid] + b_out[tid] * Ssum + conv_b[0] + qf_s[tid];
        const float S1 = redb[16] + redb[17] + redb[18] + redb[19];
        const float S2 = redb[20] + redb[21] + redb[22] + redb[23];
        const float mu = S1 * (1.0f / 256.0f);
        const float var = S2 * (1.0f / 256.0f) - mu * mu;
        out[b * 256 + tid] = (y - mu) * rsqrtf(var + 1e-5f) * ln_g[tid] + ln_b[tid];
    }
}

// ===========================================================================
extern "C" void kernel_launch(void* const* d_in, const int* in_sizes, int n_in,
                              void* d_out, int out_size, void* d_ws, size_t ws_size,
                              hipStream_t stream) {
    const float* x       = (const float*)d_in[0];
    const float* q       = (const float*)d_in[1];
    const float* w_dw    = (const float*)d_in[2];
    const float* b_dwp   = (const float*)d_in[3];
    const float* w_pw    = (const float*)d_in[4];
    const float* wk      = (const float*)d_in[5];
    const float* wv      = (const float*)d_in[6];
    const float* w_out   = (const float*)d_in[7];
    const float* b_out   = (const float*)d_in[8];
    const float* cw1     = (const float*)d_in[9];
    const float* cb1     = (const float*)d_in[10];
    const float* cw2     = (const float*)d_in[11];
    const float* cb2     = (const float*)d_in[12];
    const float* cw3     = (const float*)d_in[13];
    const float* cb3     = (const float*)d_in[14];
    const float* conv_w  = (const float*)d_in[15];
    const float* conv_b  = (const float*)d_in[16];
    const float* ln_g    = (const float*)d_in[17];
    const float* ln_b    = (const float*)d_in[18];
    float* out = (float*)d_out;

    k_all<<<256, 512, 0, stream>>>(x, q, w_dw, b_dwp, w_pw, wk, wv, w_out, b_out,
                                   cw1, cb1, cw2, cb2, cw3, cb3,
                                   conv_w, conv_b, ln_g, ln_b, out);
}